// Round 5
// baseline (431.810 us; speedup 1.0000x reference)
//
#include <hip/hip_runtime.h>
#include <hip/hip_fp16.h>

typedef _Float16 h16;
typedef __attribute__((ext_vector_type(4))) _Float16 h16x4;
typedef __attribute__((ext_vector_type(8))) _Float16 h16x8;
typedef __attribute__((ext_vector_type(4))) float f32x4;

#define DIM   1024
#define SEQ   2048
#define NKV   2
#define HD    64
#define HALFW 128
#define NQKV  1280
#define KSTG  288
#define KCOLS 272
#define VSTR  312

// ---- diagnostic repeat counts (idempotent inner loops; timing sacrificial) ----
#define PREP_REP 8
#define G1_REP   4
#define G2_REP   5
#define ATTN_REP 12

// ---------------- fused preprocess ----------------
__global__ void preprocess_kernel(const float* __restrict__ x,
                                  const float* __restrict__ bq,
                                  const float* __restrict__ bk,
                                  const float* __restrict__ bv,
                                  const float* __restrict__ Wq,
                                  const float* __restrict__ Wk,
                                  const float* __restrict__ Wv,
                                  const float* __restrict__ Wo,
                                  h16* __restrict__ xh, float* __restrict__ bqkv,
                                  h16* __restrict__ wqkvt, h16* __restrict__ wot)
{
    __shared__ float tile[32][33];
    const int tid = threadIdx.x;
    const int blk = blockIdx.x;
    for (int rep = 0; rep < PREP_REP; ++rep) {
        __syncthreads();
        if (blk < 2048) {
            int i = blk * 256 + tid;
            size_t base = (size_t)i * 8;
            float4 a = *(const float4*)(x + base);
            float4 b = *(const float4*)(x + base + 4);
            h16x8 o = { (h16)a.x,(h16)a.y,(h16)a.z,(h16)a.w,
                        (h16)b.x,(h16)b.y,(h16)b.z,(h16)b.w };
            *(h16x8*)(xh + base) = o;
            if (i < NQKV) {
                float v = (i < DIM) ? bq[i] : (i < DIM+128 ? bk[i-DIM] : bv[i-DIM-128]);
                bqkv[i] = v;
            }
        } else {
            const int tx = tid & 31, ty = tid >> 5;
            if (blk < 2048 + 1280) {
                int bid = blk - 2048;
                int n0 = (bid % 40) * 32, k0 = (bid / 40) * 32;
                const float* src; int ldn, noff;
                if (n0 < DIM)          { src = Wq; ldn = DIM; noff = n0; }
                else if (n0 < DIM+128) { src = Wk; ldn = 128; noff = n0 - DIM; }
                else                   { src = Wv; ldn = 128; noff = n0 - DIM - 128; }
#pragma unroll
                for (int i = 0; i < 4; ++i)
                    tile[ty + 8*i][tx] = src[(size_t)(k0 + ty + 8*i)*ldn + noff + tx];
                __syncthreads();
#pragma unroll
                for (int i = 0; i < 4; ++i)
                    wqkvt[(size_t)(n0 + ty + 8*i)*DIM + k0 + tx] = (h16)tile[tx][ty + 8*i];
            } else {
                int bid = blk - 3328;
                int n0 = (bid % 32) * 32, k0 = (bid / 32) * 32;
#pragma unroll
                for (int i = 0; i < 4; ++i)
                    tile[ty + 8*i][tx] = Wo[(size_t)(k0 + ty + 8*i)*DIM + n0 + tx];
                __syncthreads();
#pragma unroll
                for (int i = 0; i < 4; ++i)
                    wot[(size_t)(n0 + ty + 8*i)*DIM + k0 + tx] = (h16)tile[tx][ty + 8*i];
            }
        }
    }
}

// ------------- GEMM (r4 structure, inner-repeated) -------------
template<int MODE, int REP>
__global__ __launch_bounds__(256, 2)
void gemm_kernel(const h16* __restrict__ A, const h16* __restrict__ Bt,
                 const float* __restrict__ bias,
                 h16* __restrict__ qo, h16* __restrict__ ko, h16* __restrict__ vto,
                 float* __restrict__ co, int K, int nx)
{
    __shared__ __align__(16) h16 As[2][128*64];
    __shared__ __align__(16) h16 Bs[2][128*64];
    const int nwg = gridDim.x, bid = blockIdx.x;
    const int q8 = nwg >> 3, r8 = nwg & 7, xcd = bid & 7, off = bid >> 3;
    const int wg = (xcd < r8 ? xcd*(q8+1) : r8*(q8+1) + (xcd-r8)*q8) + off;
    const int m0 = (wg / nx) * 128, n0 = (wg % nx) * 128;
    const int tid = threadIdx.x, lane = tid & 63, wid = tid >> 6;
    const int wr = wid >> 1, wc = wid & 1;
    f32x4 acc[4][4];

    auto stage = [&](int buf, int kk) {
#pragma unroll
        for (int i = 0; i < 4; ++i) {
            int slot = i*256 + tid;
            int row = slot >> 3;
            int scol = ((slot & 7) ^ (row & 7)) * 8;
            __builtin_amdgcn_global_load_lds(
                (const __attribute__((address_space(1))) void*)(A + (size_t)(m0 + row)*K + kk + scol),
                (__attribute__((address_space(3))) void*)(&As[buf][slot*8]), 16, 0, 0);
            __builtin_amdgcn_global_load_lds(
                (const __attribute__((address_space(1))) void*)(Bt + (size_t)(n0 + row)*K + kk + scol),
                (__attribute__((address_space(3))) void*)(&Bs[buf][slot*8]), 16, 0, 0);
        }
    };
    auto compute = [&](int buf) {
#pragma unroll
        for (int k2 = 0; k2 < 2; ++k2) {
            h16x8 a[4], b[4];
#pragma unroll
            for (int mi = 0; mi < 4; ++mi) {
                int row = wr*64 + mi*16 + (lane & 15);
                int cc = (k2*4 + (lane >> 4)) ^ (row & 7);
                a[mi] = *(const h16x8*)(&As[buf][row*64 + cc*8]);
            }
#pragma unroll
            for (int ni = 0; ni < 4; ++ni) {
                int row = wc*64 + ni*16 + (lane & 15);
                int cc = (k2*4 + (lane >> 4)) ^ (row & 7);
                b[ni] = *(const h16x8*)(&Bs[buf][row*64 + cc*8]);
            }
#pragma unroll
            for (int mi = 0; mi < 4; ++mi)
#pragma unroll
                for (int ni = 0; ni < 4; ++ni)
                    acc[mi][ni] = __builtin_amdgcn_mfma_f32_16x16x32_f16(a[mi], b[ni], acc[mi][ni], 0, 0, 0);
        }
    };

    for (int rep = 0; rep < REP; ++rep) {
        __syncthreads();
#pragma unroll
        for (int mi = 0; mi < 4; ++mi)
#pragma unroll
            for (int ni = 0; ni < 4; ++ni)
                acc[mi][ni] = f32x4{0.f,0.f,0.f,0.f};
        const int ns = K >> 6;
        stage(0, 0);
        int cur = 0;
        for (int i = 0; i < ns; ++i) {
            if (i < ns-1) {
                stage(cur ^ 1, (i+1) << 6);
                asm volatile("s_waitcnt vmcnt(8)" ::: "memory");
            } else {
                asm volatile("s_waitcnt vmcnt(0)" ::: "memory");
            }
            __builtin_amdgcn_s_barrier();
            __builtin_amdgcn_sched_barrier(0);
            compute(cur);
            if (i < ns-1) {
                __builtin_amdgcn_s_barrier();
                __builtin_amdgcn_sched_barrier(0);
            }
            cur ^= 1;
        }

#pragma unroll
        for (int ni = 0; ni < 4; ++ni) {
            int n = n0 + wc*64 + ni*16 + (lane & 15);
            float bv = bias[n];
#pragma unroll
            for (int mi = 0; mi < 4; ++mi) {
                int mb = m0 + wr*64 + mi*16 + (lane >> 4)*4;
#pragma unroll
                for (int r = 0; r < 4; ++r) {
                    int m = mb + r;
                    float v = acc[mi][ni][r] + bv;
                    if (MODE == 1) {
                        co[(size_t)m*DIM + n] = v;
                    } else {
                        h16 hv = (h16)v;
                        if (n < DIM) {
                            qo[(size_t)m*DIM + n] = hv;
                        } else {
                            int nn = n - DIM;
                            int bi2 = m >> 11, s = m & 2047;
                            if (nn < 128) {
                                int g = nn >> 6, d = nn & 63;
                                ko[(((size_t)(bi2*NKV + g))*SEQ + s)*HD + d] = hv;
                            } else {
                                nn -= 128;
                                int g = nn >> 6, d = nn & 63;
                                vto[(((size_t)(bi2*NKV + g))*HD + d)*SEQ + s] = hv;
                            }
                        }
                    }
                }
            }
        }
    }
}

// ------------- sliding-window attention (r4 structure, inner-repeated) -------------
__global__ __launch_bounds__(512)
void attn_kernel(const h16* __restrict__ qb, const h16* __restrict__ kb,
                 const h16* __restrict__ vtb, h16* __restrict__ ob)
{
    extern __shared__ char smem[];
    h16* Ks  = (h16*)smem;
    h16* Vts = (h16*)(smem + 36864);
    h16* Ps  = (h16*)(smem + 36864 + 39936);
    const int tid = threadIdx.x, lane = tid & 63, wid = tid >> 6;
    const int qt = blockIdx.x, g = blockIdx.y, bi = blockIdx.z;
    const int s0 = qt * 32;
    const size_t kvbase = ((size_t)(bi*NKV + g)) * SEQ * HD;
    h16* P = Ps + wid * 16 * VSTR;
    const int h = g*8 + wid;
    const int colbase = lane & 15;
    const int rowbase = (lane >> 4) * 4;
    const int kg = rowbase;

    for (int rep = 0; rep < ATTN_REP; ++rep) {
        __syncthreads();
        for (int slot = tid; slot < KSTG*8; slot += 512) {
            int row = slot >> 3, cc = slot & 7;
            int kpos = s0 - HALFW + row;
            h16x8 val = {0,0,0,0,0,0,0,0};
            if (kpos >= 0 && kpos < SEQ)
                val = *(const h16x8*)(kb + kvbase + (size_t)kpos*HD + cc*8);
            *(h16x8*)(Ks + row*64 + ((cc ^ (row & 7)) * 8)) = val;
        }
        for (int slot = tid; slot < 64*38; slot += 512) {
            int row = slot / 38, cc = slot - row*38;
            int c0 = cc * 8;
            int kp0 = s0 - HALFW + c0;
            const h16* vrow = vtb + kvbase + (size_t)row*SEQ;
            h16x8 val = {0,0,0,0,0,0,0,0};
            if (kp0 >= 0 && kp0 + 8 <= SEQ) {
                val = *(const h16x8*)(vrow + kp0);
            } else {
#pragma unroll
                for (int j = 0; j < 8; ++j) {
                    int kp = kp0 + j;
                    val[j] = (kp >= 0 && kp < SEQ) ? vrow[kp] : (h16)0;
                }
            }
            *(h16x8*)(Vts + row*VSTR + c0) = val;
        }
        for (int i = lane; i < 256; i += 64)
            P[(i >> 4)*VSTR + KCOLS + (i & 15)] = (h16)0;
        __syncthreads();

        for (int strip = 0; strip < 2; ++strip) {
            const int ss0 = s0 + strip*16;
            h16x8 aq[2];
#pragma unroll
            for (int c = 0; c < 2; ++c)
                aq[c] = *(const h16x8*)(qb + ((size_t)(bi*SEQ + ss0 + colbase))*DIM
                                        + h*HD + c*32 + (lane >> 4)*8);

            f32x4 sc[17];
            __builtin_amdgcn_s_setprio(1);
#pragma unroll
            for (int t = 0; t < 17; ++t) {
                f32x4 z = {0.f,0.f,0.f,0.f};
#pragma unroll
                for (int c = 0; c < 2; ++c) {
                    int key = strip*16 + t*16 + colbase;
                    h16x8 kf = *(const h16x8*)(Ks + key*64 + (((c*4 + (lane >> 4)) ^ (key & 7)) * 8));
                    z = __builtin_amdgcn_mfma_f32_16x16x32_f16(kf, aq[c], z, 0, 0, 0);
                }
                sc[t] = z;
            }
            __builtin_amdgcn_s_setprio(0);

            float mx = -1e30f;
#pragma unroll
            for (int r = 0; r < 4; ++r) {
                float v0  = (kg + r >= colbase) ? sc[0][r]  : -1e30f;
                float v16 = (kg + r <  colbase) ? sc[16][r] : -1e30f;
                sc[0][r] = v0; sc[16][r] = v16;
                mx = fmaxf(mx, fmaxf(v0, v16));
            }
#pragma unroll
            for (int t = 1; t < 16; ++t)
#pragma unroll
                for (int r = 0; r < 4; ++r) mx = fmaxf(mx, sc[t][r]);
            mx = fmaxf(mx, __shfl_xor(mx, 16));
            mx = fmaxf(mx, __shfl_xor(mx, 32));
            float sum = 0.f;
#pragma unroll
            for (int t = 0; t < 17; ++t)
#pragma unroll
                for (int r = 0; r < 4; ++r) {
                    float p = __expf(sc[t][r] - mx);
                    sc[t][r] = p;
                    sum += p;
                }
            sum += __shfl_xor(sum, 16);
            sum += __shfl_xor(sum, 32);
            float inv = 1.0f / sum;

#pragma unroll
            for (int t = 0; t < 17; ++t) {
                h16x4 pk = { (h16)(sc[t][0]*inv), (h16)(sc[t][1]*inv),
                             (h16)(sc[t][2]*inv), (h16)(sc[t][3]*inv) };
                *(h16x4*)(P + colbase*VSTR + t*16 + kg) = pk;
            }

            f32x4 ao[4] = {};
            __builtin_amdgcn_s_setprio(1);
#pragma unroll
            for (int c = 0; c < 9; ++c) {
                h16x8 pa = *(const h16x8*)(P + colbase*VSTR + c*32 + (lane >> 4)*8);
                int vcol = strip*16 + c*32 + (lane >> 4)*8;
#pragma unroll
                for (int t2 = 0; t2 < 4; ++t2) {
                    h16x8 vb = *(const h16x8*)(Vts + (t2*16 + colbase)*VSTR + vcol);
                    ao[t2] = __builtin_amdgcn_mfma_f32_16x16x32_f16(pa, vb, ao[t2], 0, 0, 0);
                }
            }
            __builtin_amdgcn_s_setprio(0);
#pragma unroll
            for (int t2 = 0; t2 < 4; ++t2)
#pragma unroll
                for (int r = 0; r < 4; ++r)
                    ob[((size_t)(bi*SEQ + ss0 + rowbase + r))*DIM + h*HD + t2*16 + colbase]
                        = (h16)ao[t2][r];
            if (strip == 0) __syncthreads();
        }
    }
}

extern "C" void kernel_launch(void* const* d_in, const int* in_sizes, int n_in,
                              void* d_out, int out_size, void* d_ws, size_t ws_size,
                              hipStream_t stream)
{
    const float* x  = (const float*)d_in[0];
    const float* Wq = (const float*)d_in[1];
    const float* bq = (const float*)d_in[2];
    const float* Wk = (const float*)d_in[3];
    const float* bk = (const float*)d_in[4];
    const float* Wv = (const float*)d_in[5];
    const float* bv = (const float*)d_in[6];
    const float* Wo = (const float*)d_in[7];
    const float* bo = (const float*)d_in[8];
    float* out = (float*)d_out;
    char* ws = (char*)d_ws;

    h16*   xh    = (h16*)(ws);
    h16*   wqkvt = (h16*)(ws + 8388608);
    h16*   wot   = (h16*)(ws + 11010048);
    float* bqkv  = (float*)(ws + 13107200);
    h16*   q_b   = (h16*)(ws + 13112320);
    h16*   k_b   = (h16*)(ws + 21500928);
    h16*   vt_b  = (h16*)(ws + 22549504);
    h16*   att_b = (h16*)(ws + 23598080);

    preprocess_kernel<<<4352, 256, 0, stream>>>(x, bq, bk, bv, Wq, Wk, Wv, Wo,
                                                xh, bqkv, wqkvt, wot);
    gemm_kernel<0, G1_REP><<<320, 256, 0, stream>>>(xh, wqkvt, bqkv,
                                                    q_b, k_b, vt_b, nullptr, DIM, 10);
    hipFuncSetAttribute((const void*)attn_kernel,
                        hipFuncAttributeMaxDynamicSharedMemorySize, 156672);
    attn_kernel<<<dim3(64,2,2), 512, 156672, stream>>>(q_b, k_b, vt_b, att_b);
    gemm_kernel<1, G2_REP><<<256, 256, 0, stream>>>(att_b, wot, bo,
                                                    nullptr, nullptr, nullptr, out, DIM, 8);
}

// Round 6
// 73.518 us; speedup vs baseline: 5.8736x; 5.8736x over previous
//
#include <hip/hip_runtime.h>
#include <hip/hip_fp16.h>

typedef _Float16 h16;
typedef __attribute__((ext_vector_type(4))) _Float16 h16x4;
typedef __attribute__((ext_vector_type(8))) _Float16 h16x8;
typedef __attribute__((ext_vector_type(4))) float f32x4;

#define DIM   1024
#define SEQ   2048
#define NKV   2
#define HD    64
#define HALFW 128
#define NQKV  1280
#define KSTG  288
#define KCOLS 272
#define VSTR  312

// ---------------- fused preprocess ----------------
__global__ void preprocess_kernel(const float* __restrict__ x,
                                  const float* __restrict__ bq,
                                  const float* __restrict__ bk,
                                  const float* __restrict__ bv,
                                  const float* __restrict__ Wq,
                                  const float* __restrict__ Wk,
                                  const float* __restrict__ Wv,
                                  const float* __restrict__ Wo,
                                  h16* __restrict__ xh, float* __restrict__ bqkv,
                                  h16* __restrict__ wqkvt, h16* __restrict__ wot)
{
    __shared__ float tile[32][33];
    const int tid = threadIdx.x;
    const int blk = blockIdx.x;
    if (blk < 2048) {
        int i = blk * 256 + tid;
        size_t base = (size_t)i * 8;
        float4 a = *(const float4*)(x + base);
        float4 b = *(const float4*)(x + base + 4);
        h16x8 o = { (h16)a.x,(h16)a.y,(h16)a.z,(h16)a.w,
                    (h16)b.x,(h16)b.y,(h16)b.z,(h16)b.w };
        *(h16x8*)(xh + base) = o;
        if (i < NQKV) {
            float v = (i < DIM) ? bq[i] : (i < DIM+128 ? bk[i-DIM] : bv[i-DIM-128]);
            bqkv[i] = v;
        }
        return;
    }
    const int tx = tid & 31, ty = tid >> 5;
    if (blk < 2048 + 1280) {
        int bid = blk - 2048;
        int n0 = (bid % 40) * 32, k0 = (bid / 40) * 32;
        const float* src; int ldn, noff;
        if (n0 < DIM)          { src = Wq; ldn = DIM; noff = n0; }
        else if (n0 < DIM+128) { src = Wk; ldn = 128; noff = n0 - DIM; }
        else                   { src = Wv; ldn = 128; noff = n0 - DIM - 128; }
#pragma unroll
        for (int i = 0; i < 4; ++i)
            tile[ty + 8*i][tx] = src[(size_t)(k0 + ty + 8*i)*ldn + noff + tx];
        __syncthreads();
#pragma unroll
        for (int i = 0; i < 4; ++i)
            wqkvt[(size_t)(n0 + ty + 8*i)*DIM + k0 + tx] = (h16)tile[tx][ty + 8*i];
    } else {
        int bid = blk - 3328;
        int n0 = (bid % 32) * 32, k0 = (bid / 32) * 32;
#pragma unroll
        for (int i = 0; i < 4; ++i)
            tile[ty + 8*i][tx] = Wo[(size_t)(k0 + ty + 8*i)*DIM + n0 + tx];
        __syncthreads();
#pragma unroll
        for (int i = 0; i < 4; ++i)
            wot[(size_t)(n0 + ty + 8*i)*DIM + k0 + tx] = (h16)tile[tx][ty + 8*i];
    }
}

// ------------- v transpose: v [b][g][s][d] -> vt [b][g][d][s] -------------
__global__ void vtrans_kernel(const h16* __restrict__ v, h16* __restrict__ vt)
{
    __shared__ h16 tile[32][33];
    const int s0 = blockIdx.x * 32, d0 = blockIdx.y * 32, bg = blockIdx.z;
    const h16* src = v  + (size_t)bg * SEQ * HD;
    h16*       dst = vt + (size_t)bg * SEQ * HD;
    const int tx = threadIdx.x & 31, ty = threadIdx.x >> 5;   // 32 x 8
#pragma unroll
    for (int i = 0; i < 4; ++i)
        tile[ty + 8*i][tx] = src[(size_t)(s0 + ty + 8*i)*HD + d0 + tx];
    __syncthreads();
#pragma unroll
    for (int i = 0; i < 4; ++i)
        dst[(size_t)(d0 + ty + 8*i)*SEQ + s0 + tx] = tile[tx][ty + 8*i];
}

// ------------- GEMM: C = A[M][K] * Bt[N][K]^T + bias -------------
// 2-phase double-buffer with counted vmcnt: stage(next) -> vmcnt(8) ->
// barrier -> compute(cur) -> barrier.
// MODE 0: q [m][n] fp16, k AND v [b][g][s][d] fp16 (all contiguous-ish writes)
// MODE 1: fp32 out + bias
template<int MODE>
__global__ __launch_bounds__(256, 2)
void gemm_kernel(const h16* __restrict__ A, const h16* __restrict__ Bt,
                 const float* __restrict__ bias,
                 h16* __restrict__ qo, h16* __restrict__ ko, h16* __restrict__ vo,
                 float* __restrict__ co, int K, int nx)
{
    __shared__ __align__(16) h16 As[2][128*64];
    __shared__ __align__(16) h16 Bs[2][128*64];
    const int nwg = gridDim.x, bid = blockIdx.x;
    const int q8 = nwg >> 3, r8 = nwg & 7, xcd = bid & 7, off = bid >> 3;
    const int wg = (xcd < r8 ? xcd*(q8+1) : r8*(q8+1) + (xcd-r8)*q8) + off;
    const int m0 = (wg / nx) * 128, n0 = (wg % nx) * 128;
    const int tid = threadIdx.x, lane = tid & 63, wid = tid >> 6;
    const int wr = wid >> 1, wc = wid & 1;
    f32x4 acc[4][4] = {};

    auto stage = [&](int buf, int kk) {
#pragma unroll
        for (int i = 0; i < 4; ++i) {
            int slot = i*256 + tid;
            int row = slot >> 3;
            int scol = ((slot & 7) ^ (row & 7)) * 8;
            __builtin_amdgcn_global_load_lds(
                (const __attribute__((address_space(1))) void*)(A + (size_t)(m0 + row)*K + kk + scol),
                (__attribute__((address_space(3))) void*)(&As[buf][slot*8]), 16, 0, 0);
            __builtin_amdgcn_global_load_lds(
                (const __attribute__((address_space(1))) void*)(Bt + (size_t)(n0 + row)*K + kk + scol),
                (__attribute__((address_space(3))) void*)(&Bs[buf][slot*8]), 16, 0, 0);
        }
    };
    auto compute = [&](int buf) {
#pragma unroll
        for (int k2 = 0; k2 < 2; ++k2) {
            h16x8 a[4], b[4];
#pragma unroll
            for (int mi = 0; mi < 4; ++mi) {
                int row = wr*64 + mi*16 + (lane & 15);
                int cc = (k2*4 + (lane >> 4)) ^ (row & 7);
                a[mi] = *(const h16x8*)(&As[buf][row*64 + cc*8]);
            }
#pragma unroll
            for (int ni = 0; ni < 4; ++ni) {
                int row = wc*64 + ni*16 + (lane & 15);
                int cc = (k2*4 + (lane >> 4)) ^ (row & 7);
                b[ni] = *(const h16x8*)(&Bs[buf][row*64 + cc*8]);
            }
#pragma unroll
            for (int mi = 0; mi < 4; ++mi)
#pragma unroll
                for (int ni = 0; ni < 4; ++ni)
                    acc[mi][ni] = __builtin_amdgcn_mfma_f32_16x16x32_f16(a[mi], b[ni], acc[mi][ni], 0, 0, 0);
        }
    };

    const int ns = K >> 6;
    stage(0, 0);
    int cur = 0;
    for (int i = 0; i < ns; ++i) {
        if (i < ns-1) {
            stage(cur ^ 1, (i+1) << 6);
            asm volatile("s_waitcnt vmcnt(8)" ::: "memory");
        } else {
            asm volatile("s_waitcnt vmcnt(0)" ::: "memory");
        }
        __builtin_amdgcn_s_barrier();
        __builtin_amdgcn_sched_barrier(0);
        compute(cur);
        if (i < ns-1) {
            __builtin_amdgcn_s_barrier();
            __builtin_amdgcn_sched_barrier(0);
        }
        cur ^= 1;
    }

#pragma unroll
    for (int ni = 0; ni < 4; ++ni) {
        int n = n0 + wc*64 + ni*16 + (lane & 15);
        float bv = bias[n];
#pragma unroll
        for (int mi = 0; mi < 4; ++mi) {
            int mb = m0 + wr*64 + mi*16 + (lane >> 4)*4;
#pragma unroll
            for (int r = 0; r < 4; ++r) {
                int m = mb + r;
                float v = acc[mi][ni][r] + bv;
                if (MODE == 1) {
                    co[(size_t)m*DIM + n] = v;
                } else {
                    h16 hv = (h16)v;
                    if (n < DIM) {
                        qo[(size_t)m*DIM + n] = hv;
                    } else {
                        int nn = n - DIM;
                        int bi2 = m >> 11, s = m & 2047;
                        int g = (nn & 127) >> 6, d = nn & 63;
                        h16* dstp = (nn < 128) ? ko : vo;
                        dstp[(((size_t)(bi2*NKV + g))*SEQ + s)*HD + d] = hv;
                    }
                }
            }
        }
    }
}

// ------------- sliding-window attention (r4 structure, unchanged) -------------
__global__ __launch_bounds__(512)
void attn_kernel(const h16* __restrict__ qb, const h16* __restrict__ kb,
                 const h16* __restrict__ vtb, h16* __restrict__ ob)
{
    extern __shared__ char smem[];
    h16* Ks  = (h16*)smem;                          // 288*64*2  = 36864 B
    h16* Vts = (h16*)(smem + 36864);                // 64*312*2  = 39936 B
    h16* Ps  = (h16*)(smem + 36864 + 39936);        // 8*16*312*2 = 79872 B
    const int tid = threadIdx.x, lane = tid & 63, wid = tid >> 6;
    const int qt = blockIdx.x, g = blockIdx.y, bi = blockIdx.z;
    const int s0 = qt * 32;
    const size_t kvbase = ((size_t)(bi*NKV + g)) * SEQ * HD;

    for (int slot = tid; slot < KSTG*8; slot += 512) {
        int row = slot >> 3, cc = slot & 7;
        int kpos = s0 - HALFW + row;
        h16x8 val = {0,0,0,0,0,0,0,0};
        if (kpos >= 0 && kpos < SEQ)
            val = *(const h16x8*)(kb + kvbase + (size_t)kpos*HD + cc*8);
        *(h16x8*)(Ks + row*64 + ((cc ^ (row & 7)) * 8)) = val;
    }
    for (int slot = tid; slot < 64*38; slot += 512) {
        int row = slot / 38, cc = slot - row*38;
        int c0 = cc * 8;
        int kp0 = s0 - HALFW + c0;
        const h16* vrow = vtb + kvbase + (size_t)row*SEQ;
        h16x8 val = {0,0,0,0,0,0,0,0};
        if (kp0 >= 0 && kp0 + 8 <= SEQ) {
            val = *(const h16x8*)(vrow + kp0);
        } else {
#pragma unroll
            for (int j = 0; j < 8; ++j) {
                int kp = kp0 + j;
                val[j] = (kp >= 0 && kp < SEQ) ? vrow[kp] : (h16)0;
            }
        }
        *(h16x8*)(Vts + row*VSTR + c0) = val;
    }
    h16* P = Ps + wid * 16 * VSTR;
    for (int i = lane; i < 256; i += 64)
        P[(i >> 4)*VSTR + KCOLS + (i & 15)] = (h16)0;
    __syncthreads();

    const int h = g*8 + wid;
    const int colbase = lane & 15;
    const int rowbase = (lane >> 4) * 4;
    const int kg = rowbase;

    for (int strip = 0; strip < 2; ++strip) {
        const int ss0 = s0 + strip*16;
        h16x8 aq[2];
#pragma unroll
        for (int c = 0; c < 2; ++c)
            aq[c] = *(const h16x8*)(qb + ((size_t)(bi*SEQ + ss0 + colbase))*DIM
                                    + h*HD + c*32 + (lane >> 4)*8);

        f32x4 sc[17];
        __builtin_amdgcn_s_setprio(1);
#pragma unroll
        for (int t = 0; t < 17; ++t) {
            f32x4 z = {0.f,0.f,0.f,0.f};
#pragma unroll
            for (int c = 0; c < 2; ++c) {
                int key = strip*16 + t*16 + colbase;
                h16x8 kf = *(const h16x8*)(Ks + key*64 + (((c*4 + (lane >> 4)) ^ (key & 7)) * 8));
                z = __builtin_amdgcn_mfma_f32_16x16x32_f16(kf, aq[c], z, 0, 0, 0);
            }
            sc[t] = z;
        }
        __builtin_amdgcn_s_setprio(0);

        float mx = -1e30f;
#pragma unroll
        for (int r = 0; r < 4; ++r) {
            float v0  = (kg + r >= colbase) ? sc[0][r]  : -1e30f;
            float v16 = (kg + r <  colbase) ? sc[16][r] : -1e30f;
            sc[0][r] = v0; sc[16][r] = v16;
            mx = fmaxf(mx, fmaxf(v0, v16));
        }
#pragma unroll
        for (int t = 1; t < 16; ++t)
#pragma unroll
            for (int r = 0; r < 4; ++r) mx = fmaxf(mx, sc[t][r]);
        mx = fmaxf(mx, __shfl_xor(mx, 16));
        mx = fmaxf(mx, __shfl_xor(mx, 32));
        float sum = 0.f;
#pragma unroll
        for (int t = 0; t < 17; ++t)
#pragma unroll
            for (int r = 0; r < 4; ++r) {
                float p = __expf(sc[t][r] - mx);
                sc[t][r] = p;
                sum += p;
            }
        sum += __shfl_xor(sum, 16);
        sum += __shfl_xor(sum, 32);
        float inv = 1.0f / sum;

#pragma unroll
        for (int t = 0; t < 17; ++t) {
            h16x4 pk = { (h16)(sc[t][0]*inv), (h16)(sc[t][1]*inv),
                         (h16)(sc[t][2]*inv), (h16)(sc[t][3]*inv) };
            *(h16x4*)(P + colbase*VSTR + t*16 + kg) = pk;
        }

        f32x4 ao[4] = {};
        __builtin_amdgcn_s_setprio(1);
#pragma unroll
        for (int c = 0; c < 9; ++c) {
            h16x8 pa = *(const h16x8*)(P + colbase*VSTR + c*32 + (lane >> 4)*8);
            int vcol = strip*16 + c*32 + (lane >> 4)*8;
#pragma unroll
            for (int t2 = 0; t2 < 4; ++t2) {
                h16x8 vb = *(const h16x8*)(Vts + (t2*16 + colbase)*VSTR + vcol);
                ao[t2] = __builtin_amdgcn_mfma_f32_16x16x32_f16(pa, vb, ao[t2], 0, 0, 0);
            }
        }
        __builtin_amdgcn_s_setprio(0);
#pragma unroll
        for (int t2 = 0; t2 < 4; ++t2)
#pragma unroll
            for (int r = 0; r < 4; ++r)
                ob[((size_t)(bi*SEQ + ss0 + rowbase + r))*DIM + h*HD + t2*16 + colbase]
                    = (h16)ao[t2][r];
        if (strip == 0) __syncthreads();
    }
}

extern "C" void kernel_launch(void* const* d_in, const int* in_sizes, int n_in,
                              void* d_out, int out_size, void* d_ws, size_t ws_size,
                              hipStream_t stream)
{
    const float* x  = (const float*)d_in[0];
    const float* Wq = (const float*)d_in[1];
    const float* bq = (const float*)d_in[2];
    const float* Wk = (const float*)d_in[3];
    const float* bk = (const float*)d_in[4];
    const float* Wv = (const float*)d_in[5];
    const float* bv = (const float*)d_in[6];
    const float* Wo = (const float*)d_in[7];
    const float* bo = (const float*)d_in[8];
    float* out = (float*)d_out;
    char* ws = (char*)d_ws;

    h16*   xh    = (h16*)(ws);                 //  x fp16 [4096][1024]
    h16*   wqkvt = (h16*)(ws + 8388608);       //  Wqkv^T [1280][1024]
    h16*   wot   = (h16*)(ws + 11010048);      //  Wo^T [1024][1024]
    float* bqkv  = (float*)(ws + 13107200);
    h16*   q_b   = (h16*)(ws + 13112320);      //  q [4096][1024]
    h16*   k_b   = (h16*)(ws + 21500928);      //  k [b][g][s][64]
    h16*   vt_b  = (h16*)(ws + 22549504);      //  v^T [b][g][64][s]
    h16*   att_b = (h16*)(ws + 23598080);      //  attn out [4096][1024]
    h16*   v_b   = att_b;                      //  v [b][g][s][64] (aliases att_b:
                                               //  dead before attn writes att_b)

    preprocess_kernel<<<4352, 256, 0, stream>>>(x, bq, bk, bv, Wq, Wk, Wv, Wo,
                                                xh, bqkv, wqkvt, wot);
    gemm_kernel<0><<<320, 256, 0, stream>>>(xh, wqkvt, bqkv,
                                            q_b, k_b, v_b, nullptr, DIM, 10);
    vtrans_kernel<<<dim3(64, 2, 4), 256, 0, stream>>>(v_b, vt_b);
    hipFuncSetAttribute((const void*)attn_kernel,
                        hipFuncAttributeMaxDynamicSharedMemorySize, 156672);
    attn_kernel<<<dim3(64,2,2), 512, 156672, stream>>>(q_b, k_b, vt_b, att_b);
    gemm_kernel<1><<<256, 256, 0, stream>>>(att_b, wot, bo,
                                            nullptr, nullptr, nullptr, out, DIM, 8);
}

// Round 7
// 68.822 us; speedup vs baseline: 6.2743x; 1.0682x over previous
//
#include <hip/hip_runtime.h>
#include <hip/hip_fp16.h>

typedef _Float16 h16;
typedef __attribute__((ext_vector_type(4))) _Float16 h16x4;
typedef __attribute__((ext_vector_type(8))) _Float16 h16x8;
typedef __attribute__((ext_vector_type(4))) float f32x4;

#define DIM   1024
#define SEQ   2048
#define NKV   2
#define HD    64
#define HALFW 128
#define NQKV  1280
#define KSTG  288
#define KCOLS 272
#define VSTR  312
#define LOG2E 1.4426950408889634f

// ---------------- fused preprocess (Wq/bq pre-scaled by log2e) ----------------
__global__ void preprocess_kernel(const float* __restrict__ x,
                                  const float* __restrict__ bq,
                                  const float* __restrict__ bk,
                                  const float* __restrict__ bv,
                                  const float* __restrict__ Wq,
                                  const float* __restrict__ Wk,
                                  const float* __restrict__ Wv,
                                  const float* __restrict__ Wo,
                                  h16* __restrict__ xh, float* __restrict__ bqkv,
                                  h16* __restrict__ wqkvt, h16* __restrict__ wot)
{
    __shared__ float tile[32][33];
    const int tid = threadIdx.x;
    const int blk = blockIdx.x;
    if (blk < 2048) {
        int i = blk * 256 + tid;
        size_t base = (size_t)i * 8;
        float4 a = *(const float4*)(x + base);
        float4 b = *(const float4*)(x + base + 4);
        h16x8 o = { (h16)a.x,(h16)a.y,(h16)a.z,(h16)a.w,
                    (h16)b.x,(h16)b.y,(h16)b.z,(h16)b.w };
        *(h16x8*)(xh + base) = o;
        if (i < NQKV) {
            float v = (i < DIM) ? bq[i] * LOG2E
                                : (i < DIM+128 ? bk[i-DIM] : bv[i-DIM-128]);
            bqkv[i] = v;
        }
        return;
    }
    const int tx = tid & 31, ty = tid >> 5;
    if (blk < 2048 + 1280) {
        int bid = blk - 2048;
        int n0 = (bid % 40) * 32, k0 = (bid / 40) * 32;
        const float* src; int ldn, noff; float scl;
        if (n0 < DIM)          { src = Wq; ldn = DIM; noff = n0; scl = LOG2E; }
        else if (n0 < DIM+128) { src = Wk; ldn = 128; noff = n0 - DIM; scl = 1.f; }
        else                   { src = Wv; ldn = 128; noff = n0 - DIM - 128; scl = 1.f; }
#pragma unroll
        for (int i = 0; i < 4; ++i)
            tile[ty + 8*i][tx] = src[(size_t)(k0 + ty + 8*i)*ldn + noff + tx] * scl;
        __syncthreads();
#pragma unroll
        for (int i = 0; i < 4; ++i)
            wqkvt[(size_t)(n0 + ty + 8*i)*DIM + k0 + tx] = (h16)tile[tx][ty + 8*i];
    } else {
        int bid = blk - 3328;
        int n0 = (bid % 32) * 32, k0 = (bid / 32) * 32;
#pragma unroll
        for (int i = 0; i < 4; ++i)
            tile[ty + 8*i][tx] = Wo[(size_t)(k0 + ty + 8*i)*DIM + n0 + tx];
        __syncthreads();
#pragma unroll
        for (int i = 0; i < 4; ++i)
            wot[(size_t)(n0 + ty + 8*i)*DIM + k0 + tx] = (h16)tile[tx][ty + 8*i];
    }
}

// ------------- v transpose: v [b][g][s][d] -> vt [b][g][d][s] -------------
__global__ void vtrans_kernel(const h16* __restrict__ v, h16* __restrict__ vt)
{
    __shared__ h16 tile[32][33];
    const int s0 = blockIdx.x * 32, d0 = blockIdx.y * 32, bg = blockIdx.z;
    const h16* src = v  + (size_t)bg * SEQ * HD;
    h16*       dst = vt + (size_t)bg * SEQ * HD;
    const int tx = threadIdx.x & 31, ty = threadIdx.x >> 5;
#pragma unroll
    for (int i = 0; i < 4; ++i)
        tile[ty + 8*i][tx] = src[(size_t)(s0 + ty + 8*i)*HD + d0 + tx];
    __syncthreads();
#pragma unroll
    for (int i = 0; i < 4; ++i)
        dst[(size_t)(d0 + ty + 8*i)*SEQ + s0 + tx] = tile[tx][ty + 8*i];
}

// ------------- GEMM: 8-wave 128xBN tile, BK=64, depth-3 counted-vmcnt pipeline ---
// grid exactly 256 (1 block/CU). Waves 4x2 (rows x cols): per wave 32 x BN/2.
// MODE 0: q/k/v scatter epilogue fp16; MODE 1: fp32 + bias.
// BSTG = staged B rows (192 for BN=160: exact 3 loads/thread; over-reads stay in ws).
template<int MODE, int BN, int BSTG>
__global__ __launch_bounds__(512)
void gemm_kernel(const h16* __restrict__ A, const h16* __restrict__ Bt,
                 const float* __restrict__ bias,
                 h16* __restrict__ qo, h16* __restrict__ ko, h16* __restrict__ vo,
                 float* __restrict__ co, int K)
{
    constexpr int NI   = BN / 32;           // b-frags per wave (5 or 4)
    constexpr int ABUF = 128 * 64;          // h16 per A buffer
    constexpr int BBUF = BSTG * 64;
    constexpr int BUFSZ = ABUF + BBUF;
    extern __shared__ __align__(16) h16 lds[];

    const int bid = blockIdx.x;
    const int wg = (bid & 7) * 32 + (bid >> 3);          // XCD swizzle (256%8==0)
    const int m0 = (wg >> 3) * 128, n0 = (wg & 7) * BN;
    const int tid = threadIdx.x, lane = tid & 63, wid = tid >> 6;
    const int wr = wid >> 1, wc = wid & 1;               // 4 x 2 wave grid
    f32x4 acc[2][NI] = {};

    auto stage = [&](int buf, int kk) {
        h16* Ab = lds + buf * BUFSZ;
        h16* Bb = Ab + ABUF;
#pragma unroll
        for (int i = 0; i < 2; ++i) {                     // A: 128 rows
            int slot = i*512 + tid;
            int row = slot >> 3;
            int scol = ((slot & 7) ^ (row & 7)) * 8;
            __builtin_amdgcn_global_load_lds(
                (const __attribute__((address_space(1))) void*)(A + (size_t)(m0 + row)*K + kk + scol),
                (__attribute__((address_space(3))) void*)(Ab + slot*8), 16, 0, 0);
        }
#pragma unroll
        for (int i = 0; i < BSTG/64; ++i) {               // B: BSTG rows
            int slot = i*512 + tid;
            int row = slot >> 3;
            int scol = ((slot & 7) ^ (row & 7)) * 8;
            __builtin_amdgcn_global_load_lds(
                (const __attribute__((address_space(1))) void*)(Bt + (size_t)(n0 + row)*K + kk + scol),
                (__attribute__((address_space(3))) void*)(Bb + slot*8), 16, 0, 0);
        }
    };
    auto compute = [&](int buf) {
        const h16* Ab = lds + buf * BUFSZ;
        const h16* Bb = Ab + ABUF;
#pragma unroll
        for (int k2 = 0; k2 < 2; ++k2) {
            h16x8 a[2], b[NI];
#pragma unroll
            for (int mi = 0; mi < 2; ++mi) {
                int row = wr*32 + mi*16 + (lane & 15);
                int cc = (k2*4 + (lane >> 4)) ^ (row & 7);
                a[mi] = *(const h16x8*)(Ab + row*64 + cc*8);
            }
#pragma unroll
            for (int ni = 0; ni < NI; ++ni) {
                int row = wc*(BN/2) + ni*16 + (lane & 15);
                int cc = (k2*4 + (lane >> 4)) ^ (row & 7);
                b[ni] = *(const h16x8*)(Bb + row*64 + cc*8);
            }
#pragma unroll
            for (int mi = 0; mi < 2; ++mi)
#pragma unroll
                for (int ni = 0; ni < NI; ++ni)
                    acc[mi][ni] = __builtin_amdgcn_mfma_f32_16x16x32_f16(a[mi], b[ni], acc[mi][ni], 0, 0, 0);
        }
    };

    const int ns = K >> 6;                                // 16 steps
    stage(0, 0);
    stage(1, 64);
    int cb = 0, sb = 2;
    for (int i = 0; i < ns; ++i) {
        const int rem = ns - 1 - i;
        if (i + 2 < ns) { stage(sb, (i+2) << 6); sb = (sb == 2) ? 0 : sb + 1; }
        if (rem >= 2) {
            if constexpr (BSTG == 192) asm volatile("s_waitcnt vmcnt(10)" ::: "memory");
            else                       asm volatile("s_waitcnt vmcnt(8)"  ::: "memory");
        } else if (rem == 1) {
            if constexpr (BSTG == 192) asm volatile("s_waitcnt vmcnt(5)" ::: "memory");
            else                       asm volatile("s_waitcnt vmcnt(4)" ::: "memory");
        } else {
            asm volatile("s_waitcnt vmcnt(0)" ::: "memory");
        }
        __builtin_amdgcn_s_barrier();
        __builtin_amdgcn_sched_barrier(0);
        compute(cb); cb = (cb == 2) ? 0 : cb + 1;
        if (rem) {
            __builtin_amdgcn_s_barrier();
            __builtin_amdgcn_sched_barrier(0);
        }
    }

#pragma unroll
    for (int ni = 0; ni < NI; ++ni) {
        int n = n0 + wc*(BN/2) + ni*16 + (lane & 15);
        float bv = bias[n];
#pragma unroll
        for (int mi = 0; mi < 2; ++mi) {
            int mb = m0 + wr*32 + mi*16 + (lane >> 4)*4;
#pragma unroll
            for (int r = 0; r < 4; ++r) {
                int m = mb + r;
                float v = acc[mi][ni][r] + bv;
                if (MODE == 1) {
                    co[(size_t)m*DIM + n] = v;
                } else {
                    h16 hv = (h16)v;
                    if (n < DIM) {
                        qo[(size_t)m*DIM + n] = hv;
                    } else {
                        int nn = n - DIM;
                        int bi2 = m >> 11, s = m & 2047;
                        int g = (nn & 127) >> 6, d = nn & 63;
                        h16* dstp = (nn < 128) ? ko : vo;
                        dstp[(((size_t)(bi2*NKV + g))*SEQ + s)*HD + d] = hv;
                    }
                }
            }
        }
    }
}

// ------------- sliding-window attention (r4 structure + exp2) -------------
__global__ __launch_bounds__(512)
void attn_kernel(const h16* __restrict__ qb, const h16* __restrict__ kb,
                 const h16* __restrict__ vtb, h16* __restrict__ ob)
{
    extern __shared__ char smem[];
    h16* Ks  = (h16*)smem;                          // 288*64*2  = 36864 B
    h16* Vts = (h16*)(smem + 36864);                // 64*312*2  = 39936 B
    h16* Ps  = (h16*)(smem + 36864 + 39936);        // 8*16*312*2 = 79872 B
    const int tid = threadIdx.x, lane = tid & 63, wid = tid >> 6;
    const int qt = blockIdx.x, g = blockIdx.y, bi = blockIdx.z;
    const int s0 = qt * 32;
    const size_t kvbase = ((size_t)(bi*NKV + g)) * SEQ * HD;

    for (int slot = tid; slot < KSTG*8; slot += 512) {
        int row = slot >> 3, cc = slot & 7;
        int kpos = s0 - HALFW + row;
        h16x8 val = {0,0,0,0,0,0,0,0};
        if (kpos >= 0 && kpos < SEQ)
            val = *(const h16x8*)(kb + kvbase + (size_t)kpos*HD + cc*8);
        *(h16x8*)(Ks + row*64 + ((cc ^ (row & 7)) * 8)) = val;
    }
    for (int slot = tid; slot < 64*38; slot += 512) {
        int row = slot / 38, cc = slot - row*38;
        int c0 = cc * 8;
        int kp0 = s0 - HALFW + c0;
        const h16* vrow = vtb + kvbase + (size_t)row*SEQ;
        h16x8 val = {0,0,0,0,0,0,0,0};
        if (kp0 >= 0 && kp0 + 8 <= SEQ) {
            val = *(const h16x8*)(vrow + kp0);
        } else {
#pragma unroll
            for (int j = 0; j < 8; ++j) {
                int kp = kp0 + j;
                val[j] = (kp >= 0 && kp < SEQ) ? vrow[kp] : (h16)0;
            }
        }
        *(h16x8*)(Vts + row*VSTR + c0) = val;
    }
    h16* P = Ps + wid * 16 * VSTR;
    for (int i = lane; i < 256; i += 64)
        P[(i >> 4)*VSTR + KCOLS + (i & 15)] = (h16)0;
    __syncthreads();

    const int h = g*8 + wid;
    const int colbase = lane & 15;
    const int rowbase = (lane >> 4) * 4;
    const int kg = rowbase;

    for (int strip = 0; strip < 2; ++strip) {
        const int ss0 = s0 + strip*16;
        h16x8 aq[2];
#pragma unroll
        for (int c = 0; c < 2; ++c)
            aq[c] = *(const h16x8*)(qb + ((size_t)(bi*SEQ + ss0 + colbase))*DIM
                                    + h*HD + c*32 + (lane >> 4)*8);

        f32x4 sc[17];
        __builtin_amdgcn_s_setprio(1);
#pragma unroll
        for (int t = 0; t < 17; ++t) {
            f32x4 z = {0.f,0.f,0.f,0.f};
#pragma unroll
            for (int c = 0; c < 2; ++c) {
                int key = strip*16 + t*16 + colbase;
                h16x8 kf = *(const h16x8*)(Ks + key*64 + (((c*4 + (lane >> 4)) ^ (key & 7)) * 8));
                z = __builtin_amdgcn_mfma_f32_16x16x32_f16(kf, aq[c], z, 0, 0, 0);
            }
            sc[t] = z;
        }
        __builtin_amdgcn_s_setprio(0);

        float mx = -1e30f;
#pragma unroll
        for (int r = 0; r < 4; ++r) {
            float v0  = (kg + r >= colbase) ? sc[0][r]  : -1e30f;
            float v16 = (kg + r <  colbase) ? sc[16][r] : -1e30f;
            sc[0][r] = v0; sc[16][r] = v16;
            mx = fmaxf(mx, fmaxf(v0, v16));
        }
#pragma unroll
        for (int t = 1; t < 16; ++t)
#pragma unroll
            for (int r = 0; r < 4; ++r) mx = fmaxf(mx, sc[t][r]);
        mx = fmaxf(mx, __shfl_xor(mx, 16));
        mx = fmaxf(mx, __shfl_xor(mx, 32));
        float sum = 0.f;
#pragma unroll
        for (int t = 0; t < 17; ++t)
#pragma unroll
            for (int r = 0; r < 4; ++r) {
                float p = exp2f(sc[t][r] - mx);   // scores pre-scaled by log2e
                sc[t][r] = p;
                sum += p;
            }
        sum += __shfl_xor(sum, 16);
        sum += __shfl_xor(sum, 32);
        float inv = 1.0f / sum;

#pragma unroll
        for (int t = 0; t < 17; ++t) {
            h16x4 pk = { (h16)(sc[t][0]*inv), (h16)(sc[t][1]*inv),
                         (h16)(sc[t][2]*inv), (h16)(sc[t][3]*inv) };
            *(h16x4*)(P + colbase*VSTR + t*16 + kg) = pk;
        }

        f32x4 ao[4] = {};
        __builtin_amdgcn_s_setprio(1);
#pragma unroll
        for (int c = 0; c < 9; ++c) {
            h16x8 pa = *(const h16x8*)(P + colbase*VSTR + c*32 + (lane >> 4)*8);
            int vcol = strip*16 + c*32 + (lane >> 4)*8;
#pragma unroll
            for (int t2 = 0; t2 < 4; ++t2) {
                h16x8 vb = *(const h16x8*)(Vts + (t2*16 + colbase)*VSTR + vcol);
                ao[t2] = __builtin_amdgcn_mfma_f32_16x16x32_f16(pa, vb, ao[t2], 0, 0, 0);
            }
        }
        __builtin_amdgcn_s_setprio(0);
#pragma unroll
        for (int t2 = 0; t2 < 4; ++t2)
#pragma unroll
            for (int r = 0; r < 4; ++r)
                ob[((size_t)(bi*SEQ + ss0 + rowbase + r))*DIM + h*HD + t2*16 + colbase]
                    = (h16)ao[t2][r];
        if (strip == 0) __syncthreads();
    }
}

extern "C" void kernel_launch(void* const* d_in, const int* in_sizes, int n_in,
                              void* d_out, int out_size, void* d_ws, size_t ws_size,
                              hipStream_t stream)
{
    const float* x  = (const float*)d_in[0];
    const float* Wq = (const float*)d_in[1];
    const float* bq = (const float*)d_in[2];
    const float* Wk = (const float*)d_in[3];
    const float* bk = (const float*)d_in[4];
    const float* Wv = (const float*)d_in[5];
    const float* bv = (const float*)d_in[6];
    const float* Wo = (const float*)d_in[7];
    const float* bo = (const float*)d_in[8];
    float* out = (float*)d_out;
    char* ws = (char*)d_ws;

    h16*   xh    = (h16*)(ws);                 //  x fp16 [4096][1024]
    h16*   wqkvt = (h16*)(ws + 8388608);       //  Wqkv^T [1280][1024] (Wq part * log2e)
    h16*   wot   = (h16*)(ws + 11010048);      //  Wo^T [1024][1024]
    float* bqkv  = (float*)(ws + 13107200);
    h16*   q_b   = (h16*)(ws + 13112320);      //  q [4096][1024]
    h16*   k_b   = (h16*)(ws + 21500928);      //  k [b][g][s][64]
    h16*   vt_b  = (h16*)(ws + 22549504);      //  v^T [b][g][64][s]
    h16*   att_b = (h16*)(ws + 23598080);      //  attn out [4096][1024]
    h16*   v_b   = att_b;                      //  v [b][g][s][64] (aliases att_b)

    preprocess_kernel<<<4352, 256, 0, stream>>>(x, bq, bk, bv, Wq, Wk, Wv, Wo,
                                                xh, bqkv, wqkvt, wot);
    hipFuncSetAttribute((const void*)(gemm_kernel<0,160,192>),
                        hipFuncAttributeMaxDynamicSharedMemorySize, 122880);
    gemm_kernel<0,160,192><<<256, 512, 122880, stream>>>(xh, wqkvt, bqkv,
                                            q_b, k_b, v_b, nullptr, DIM);
    vtrans_kernel<<<dim3(64, 2, 4), 256, 0, stream>>>(v_b, vt_b);
    hipFuncSetAttribute((const void*)attn_kernel,
                        hipFuncAttributeMaxDynamicSharedMemorySize, 156672);
    attn_kernel<<<dim3(64,2,2), 512, 156672, stream>>>(q_b, k_b, vt_b, att_b);
    hipFuncSetAttribute((const void*)(gemm_kernel<1,128,128>),
                        hipFuncAttributeMaxDynamicSharedMemorySize, 98304);
    gemm_kernel<1,128,128><<<256, 512, 98304, stream>>>(att_b, wot, bo,
                                            nullptr, nullptr, nullptr, out, DIM);
}

// Round 8
// 68.374 us; speedup vs baseline: 6.3154x; 1.0065x over previous
//
#include <hip/hip_runtime.h>
#include <hip/hip_fp16.h>

typedef _Float16 h16;
typedef __attribute__((ext_vector_type(4))) _Float16 h16x4;
typedef __attribute__((ext_vector_type(8))) _Float16 h16x8;
typedef __attribute__((ext_vector_type(4))) float f32x4;

#define DIM   1024
#define SEQ   2048
#define NKV   2
#define HD    64
#define HALFW 128
#define NQKV  1280
#define KSTG  288
#define KCOLS 272
#define VSTR  312
#define LOG2E 1.4426950408889634f

// ---------------- fused preprocess (Wq/bq pre-scaled by log2e) ----------------
__global__ void preprocess_kernel(const float* __restrict__ x,
                                  const float* __restrict__ bq,
                                  const float* __restrict__ bk,
                                  const float* __restrict__ bv,
                                  const float* __restrict__ Wq,
                                  const float* __restrict__ Wk,
                                  const float* __restrict__ Wv,
                                  const float* __restrict__ Wo,
                                  h16* __restrict__ xh, float* __restrict__ bqkv,
                                  h16* __restrict__ wqkvt, h16* __restrict__ wot)
{
    __shared__ float tile[32][33];
    const int tid = threadIdx.x;
    const int blk = blockIdx.x;
    if (blk < 2048) {
        int i = blk * 256 + tid;
        size_t base = (size_t)i * 8;
        float4 a = *(const float4*)(x + base);
        float4 b = *(const float4*)(x + base + 4);
        h16x8 o = { (h16)a.x,(h16)a.y,(h16)a.z,(h16)a.w,
                    (h16)b.x,(h16)b.y,(h16)b.z,(h16)b.w };
        *(h16x8*)(xh + base) = o;
        if (i < NQKV) {
            float v = (i < DIM) ? bq[i] * LOG2E
                                : (i < DIM+128 ? bk[i-DIM] : bv[i-DIM-128]);
            bqkv[i] = v;
        }
        return;
    }
    const int tx = tid & 31, ty = tid >> 5;
    if (blk < 2048 + 1280) {
        int bid = blk - 2048;
        int n0 = (bid % 40) * 32, k0 = (bid / 40) * 32;
        const float* src; int ldn, noff; float scl;
        if (n0 < DIM)          { src = Wq; ldn = DIM; noff = n0; scl = LOG2E; }
        else if (n0 < DIM+128) { src = Wk; ldn = 128; noff = n0 - DIM; scl = 1.f; }
        else                   { src = Wv; ldn = 128; noff = n0 - DIM - 128; scl = 1.f; }
#pragma unroll
        for (int i = 0; i < 4; ++i)
            tile[ty + 8*i][tx] = src[(size_t)(k0 + ty + 8*i)*ldn + noff + tx] * scl;
        __syncthreads();
#pragma unroll
        for (int i = 0; i < 4; ++i)
            wqkvt[(size_t)(n0 + ty + 8*i)*DIM + k0 + tx] = (h16)tile[tx][ty + 8*i];
    } else {
        int bid = blk - 3328;
        int n0 = (bid % 32) * 32, k0 = (bid / 32) * 32;
#pragma unroll
        for (int i = 0; i < 4; ++i)
            tile[ty + 8*i][tx] = Wo[(size_t)(k0 + ty + 8*i)*DIM + n0 + tx];
        __syncthreads();
#pragma unroll
        for (int i = 0; i < 4; ++i)
            wot[(size_t)(n0 + ty + 8*i)*DIM + k0 + tx] = (h16)tile[tx][ty + 8*i];
    }
}

// ------------- v transpose: v [b][g][s][d] -> vt [b][g][d][s] -------------
__global__ void vtrans_kernel(const h16* __restrict__ v, h16* __restrict__ vt)
{
    __shared__ h16 tile[32][33];
    const int s0 = blockIdx.x * 32, d0 = blockIdx.y * 32, bg = blockIdx.z;
    const h16* src = v  + (size_t)bg * SEQ * HD;
    h16*       dst = vt + (size_t)bg * SEQ * HD;
    const int tx = threadIdx.x & 31, ty = threadIdx.x >> 5;
#pragma unroll
    for (int i = 0; i < 4; ++i)
        tile[ty + 8*i][tx] = src[(size_t)(s0 + ty + 8*i)*HD + d0 + tx];
    __syncthreads();
#pragma unroll
    for (int i = 0; i < 4; ++i)
        dst[(size_t)(d0 + ty + 8*i)*SEQ + s0 + tx] = tile[tx][ty + 8*i];
}

// ------------- GEMM: 128x64 tile, BK=64, 4 waves, 2-phase counted-vmcnt -------
// 48 KB LDS -> 3 blocks/CU co-resident (the m97/m114 overlap regime).
// MODE 0: q [m][n] fp16 + k/v [b][g][s][d] fp16 scatter; MODE 1: fp32 + bias.
template<int MODE>
__global__ __launch_bounds__(256, 3)
void gemm_kernel(const h16* __restrict__ A, const h16* __restrict__ Bt,
                 const float* __restrict__ bias,
                 h16* __restrict__ qo, h16* __restrict__ ko, h16* __restrict__ vo,
                 float* __restrict__ co, int K, int nx)
{
    __shared__ __align__(16) h16 As[2][128*64];
    __shared__ __align__(16) h16 Bs[2][64*64];
    const int nwg = gridDim.x, bid = blockIdx.x;
    const int wg = (bid & 7) * (nwg >> 3) + (bid >> 3);   // XCD swizzle (nwg%8==0)
    const int m0 = (wg / nx) * 128, n0 = (wg % nx) * 64;
    const int tid = threadIdx.x, lane = tid & 63, wid = tid >> 6;
    const int wr = wid >> 1, wc = wid & 1;                // 2x2 wave grid
    f32x4 acc[4][2] = {};

    auto stage = [&](int buf, int kk) {
#pragma unroll
        for (int i = 0; i < 4; ++i) {                     // A: 128 rows x 8 chunks
            int slot = i*256 + tid;
            int row = slot >> 3;
            int scol = ((slot & 7) ^ (row & 7)) * 8;
            __builtin_amdgcn_global_load_lds(
                (const __attribute__((address_space(1))) void*)(A + (size_t)(m0 + row)*K + kk + scol),
                (__attribute__((address_space(3))) void*)(&As[buf][slot*8]), 16, 0, 0);
        }
#pragma unroll
        for (int i = 0; i < 2; ++i) {                     // B: 64 rows x 8 chunks
            int slot = i*256 + tid;
            int row = slot >> 3;
            int scol = ((slot & 7) ^ (row & 7)) * 8;
            __builtin_amdgcn_global_load_lds(
                (const __attribute__((address_space(1))) void*)(Bt + (size_t)(n0 + row)*K + kk + scol),
                (__attribute__((address_space(3))) void*)(&Bs[buf][slot*8]), 16, 0, 0);
        }
    };
    auto compute = [&](int buf) {
#pragma unroll
        for (int k2 = 0; k2 < 2; ++k2) {
            h16x8 a[4], b[2];
#pragma unroll
            for (int mi = 0; mi < 4; ++mi) {
                int row = wr*64 + mi*16 + (lane & 15);
                int cc = (k2*4 + (lane >> 4)) ^ (row & 7);
                a[mi] = *(const h16x8*)(&As[buf][row*64 + cc*8]);
            }
#pragma unroll
            for (int ni = 0; ni < 2; ++ni) {
                int row = wc*32 + ni*16 + (lane & 15);
                int cc = (k2*4 + (lane >> 4)) ^ (row & 7);
                b[ni] = *(const h16x8*)(&Bs[buf][row*64 + cc*8]);
            }
#pragma unroll
            for (int mi = 0; mi < 4; ++mi)
#pragma unroll
                for (int ni = 0; ni < 2; ++ni)
                    acc[mi][ni] = __builtin_amdgcn_mfma_f32_16x16x32_f16(a[mi], b[ni], acc[mi][ni], 0, 0, 0);
        }
    };

    const int ns = K >> 6;
    stage(0, 0);
    int cur = 0;
    for (int i = 0; i < ns; ++i) {
        if (i < ns-1) {
            stage(cur ^ 1, (i+1) << 6);                      // 6 loads in flight
            asm volatile("s_waitcnt vmcnt(6)" ::: "memory"); // prev stage landed
        } else {
            asm volatile("s_waitcnt vmcnt(0)" ::: "memory");
        }
        __builtin_amdgcn_s_barrier();
        __builtin_amdgcn_sched_barrier(0);
        compute(cur);
        if (i < ns-1) {
            __builtin_amdgcn_s_barrier();
            __builtin_amdgcn_sched_barrier(0);
        }
        cur ^= 1;
    }

#pragma unroll
    for (int ni = 0; ni < 2; ++ni) {
        int n = n0 + wc*32 + ni*16 + (lane & 15);
        float bv = bias[n];
#pragma unroll
        for (int mi = 0; mi < 4; ++mi) {
            int mb = m0 + wr*64 + mi*16 + (lane >> 4)*4;
#pragma unroll
            for (int r = 0; r < 4; ++r) {
                int m = mb + r;
                float v = acc[mi][ni][r] + bv;
                if (MODE == 1) {
                    co[(size_t)m*DIM + n] = v;
                } else {
                    h16 hv = (h16)v;
                    if (n < DIM) {
                        qo[(size_t)m*DIM + n] = hv;
                    } else {
                        int nn = n - DIM;
                        int bi2 = m >> 11, s = m & 2047;
                        int g = (nn & 127) >> 6, d = nn & 63;
                        h16* dstp = (nn < 128) ? ko : vo;
                        dstp[(((size_t)(bi2*NKV + g))*SEQ + s)*HD + d] = hv;
                    }
                }
            }
        }
    }
}

// ------------- sliding-window attention (r7 structure, unchanged) -------------
__global__ __launch_bounds__(512)
void attn_kernel(const h16* __restrict__ qb, const h16* __restrict__ kb,
                 const h16* __restrict__ vtb, h16* __restrict__ ob)
{
    extern __shared__ char smem[];
    h16* Ks  = (h16*)smem;
    h16* Vts = (h16*)(smem + 36864);
    h16* Ps  = (h16*)(smem + 36864 + 39936);
    const int tid = threadIdx.x, lane = tid & 63, wid = tid >> 6;
    const int qt = blockIdx.x, g = blockIdx.y, bi = blockIdx.z;
    const int s0 = qt * 32;
    const size_t kvbase = ((size_t)(bi*NKV + g)) * SEQ * HD;

    for (int slot = tid; slot < KSTG*8; slot += 512) {
        int row = slot >> 3, cc = slot & 7;
        int kpos = s0 - HALFW + row;
        h16x8 val = {0,0,0,0,0,0,0,0};
        if (kpos >= 0 && kpos < SEQ)
            val = *(const h16x8*)(kb + kvbase + (size_t)kpos*HD + cc*8);
        *(h16x8*)(Ks + row*64 + ((cc ^ (row & 7)) * 8)) = val;
    }
    for (int slot = tid; slot < 64*38; slot += 512) {
        int row = slot / 38, cc = slot - row*38;
        int c0 = cc * 8;
        int kp0 = s0 - HALFW + c0;
        const h16* vrow = vtb + kvbase + (size_t)row*SEQ;
        h16x8 val = {0,0,0,0,0,0,0,0};
        if (kp0 >= 0 && kp0 + 8 <= SEQ) {
            val = *(const h16x8*)(vrow + kp0);
        } else {
#pragma unroll
            for (int j = 0; j < 8; ++j) {
                int kp = kp0 + j;
                val[j] = (kp >= 0 && kp < SEQ) ? vrow[kp] : (h16)0;
            }
        }
        *(h16x8*)(Vts + row*VSTR + c0) = val;
    }
    h16* P = Ps + wid * 16 * VSTR;
    for (int i = lane; i < 256; i += 64)
        P[(i >> 4)*VSTR + KCOLS + (i & 15)] = (h16)0;
    __syncthreads();

    const int h = g*8 + wid;
    const int colbase = lane & 15;
    const int rowbase = (lane >> 4) * 4;
    const int kg = rowbase;

    for (int strip = 0; strip < 2; ++strip) {
        const int ss0 = s0 + strip*16;
        h16x8 aq[2];
#pragma unroll
        for (int c = 0; c < 2; ++c)
            aq[c] = *(const h16x8*)(qb + ((size_t)(bi*SEQ + ss0 + colbase))*DIM
                                    + h*HD + c*32 + (lane >> 4)*8);

        f32x4 sc[17];
        __builtin_amdgcn_s_setprio(1);
#pragma unroll
        for (int t = 0; t < 17; ++t) {
            f32x4 z = {0.f,0.f,0.f,0.f};
#pragma unroll
            for (int c = 0; c < 2; ++c) {
                int key = strip*16 + t*16 + colbase;
                h16x8 kf = *(const h16x8*)(Ks + key*64 + (((c*4 + (lane >> 4)) ^ (key & 7)) * 8));
                z = __builtin_amdgcn_mfma_f32_16x16x32_f16(kf, aq[c], z, 0, 0, 0);
            }
            sc[t] = z;
        }
        __builtin_amdgcn_s_setprio(0);

        float mx = -1e30f;
#pragma unroll
        for (int r = 0; r < 4; ++r) {
            float v0  = (kg + r >= colbase) ? sc[0][r]  : -1e30f;
            float v16 = (kg + r <  colbase) ? sc[16][r] : -1e30f;
            sc[0][r] = v0; sc[16][r] = v16;
            mx = fmaxf(mx, fmaxf(v0, v16));
        }
#pragma unroll
        for (int t = 1; t < 16; ++t)
#pragma unroll
            for (int r = 0; r < 4; ++r) mx = fmaxf(mx, sc[t][r]);
        mx = fmaxf(mx, __shfl_xor(mx, 16));
        mx = fmaxf(mx, __shfl_xor(mx, 32));
        float sum = 0.f;
#pragma unroll
        for (int t = 0; t < 17; ++t)
#pragma unroll
            for (int r = 0; r < 4; ++r) {
                float p = exp2f(sc[t][r] - mx);   // scores pre-scaled by log2e
                sc[t][r] = p;
                sum += p;
            }
        sum += __shfl_xor(sum, 16);
        sum += __shfl_xor(sum, 32);
        float inv = 1.0f / sum;

#pragma unroll
        for (int t = 0; t < 17; ++t) {
            h16x4 pk = { (h16)(sc[t][0]*inv), (h16)(sc[t][1]*inv),
                         (h16)(sc[t][2]*inv), (h16)(sc[t][3]*inv) };
            *(h16x4*)(P + colbase*VSTR + t*16 + kg) = pk;
        }

        f32x4 ao[4] = {};
        __builtin_amdgcn_s_setprio(1);
#pragma unroll
        for (int c = 0; c < 9; ++c) {
            h16x8 pa = *(const h16x8*)(P + colbase*VSTR + c*32 + (lane >> 4)*8);
            int vcol = strip*16 + c*32 + (lane >> 4)*8;
#pragma unroll
            for (int t2 = 0; t2 < 4; ++t2) {
                h16x8 vb = *(const h16x8*)(Vts + (t2*16 + colbase)*VSTR + vcol);
                ao[t2] = __builtin_amdgcn_mfma_f32_16x16x32_f16(pa, vb, ao[t2], 0, 0, 0);
            }
        }
        __builtin_amdgcn_s_setprio(0);
#pragma unroll
        for (int t2 = 0; t2 < 4; ++t2)
#pragma unroll
            for (int r = 0; r < 4; ++r)
                ob[((size_t)(bi*SEQ + ss0 + rowbase + r))*DIM + h*HD + t2*16 + colbase]
                    = (h16)ao[t2][r];
        if (strip == 0) __syncthreads();
    }
}

extern "C" void kernel_launch(void* const* d_in, const int* in_sizes, int n_in,
                              void* d_out, int out_size, void* d_ws, size_t ws_size,
                              hipStream_t stream)
{
    const float* x  = (const float*)d_in[0];
    const float* Wq = (const float*)d_in[1];
    const float* bq = (const float*)d_in[2];
    const float* Wk = (const float*)d_in[3];
    const float* bk = (const float*)d_in[4];
    const float* Wv = (const float*)d_in[5];
    const float* bv = (const float*)d_in[6];
    const float* Wo = (const float*)d_in[7];
    const float* bo = (const float*)d_in[8];
    float* out = (float*)d_out;
    char* ws = (char*)d_ws;

    h16*   xh    = (h16*)(ws);                 //  x fp16 [4096][1024]
    h16*   wqkvt = (h16*)(ws + 8388608);       //  Wqkv^T [1280][1024] (Wq part * log2e)
    h16*   wot   = (h16*)(ws + 11010048);      //  Wo^T [1024][1024]
    float* bqkv  = (float*)(ws + 13107200);
    h16*   q_b   = (h16*)(ws + 13112320);      //  q [4096][1024]
    h16*   k_b   = (h16*)(ws + 21500928);      //  k [b][g][s][64]
    h16*   vt_b  = (h16*)(ws + 22549504);      //  v^T [b][g][64][s]
    h16*   att_b = (h16*)(ws + 23598080);      //  attn out [4096][1024]
    h16*   v_b   = att_b;                      //  v [b][g][s][64] (aliases att_b)

    preprocess_kernel<<<4352, 256, 0, stream>>>(x, bq, bk, bv, Wq, Wk, Wv, Wo,
                                                xh, bqkv, wqkvt, wot);
    gemm_kernel<0><<<640, 256, 0, stream>>>(xh, wqkvt, bqkv,
                                            q_b, k_b, v_b, nullptr, DIM, 20);
    vtrans_kernel<<<dim3(64, 2, 4), 256, 0, stream>>>(v_b, vt_b);
    hipFuncSetAttribute((const void*)attn_kernel,
                        hipFuncAttributeMaxDynamicSharedMemorySize, 156672);
    attn_kernel<<<dim3(64,2,2), 512, 156672, stream>>>(q_b, k_b, vt_b, att_b);
    gemm_kernel<1><<<512, 256, 0, stream>>>(att_b, wot, bo,
                                            nullptr, nullptr, nullptr, out, DIM, 16);
}